// Round 23
// baseline (54.773 us; speedup 1.0000x reference)
//
#include <hip/hip_runtime.h>

#define NN     4096
#define TT     3
#define DD     20
#define EE     131072
#define ADIM   128
#define NEG    0.2f
#define NEDGE  (TT * EE)               // 393216 edges
#define NBINS  1024                    // row>>2 -> 4 rows per bin
#define RPB2   4
#define NBB    512                     // k_bin blocks
#define EPB    (NEDGE / NBB)           // 768 edges per block -> 1536 items exact
#define IPB    (2 * EPB)               // 1536
#define CAP    512                     // CSR entries per row (max ~260)
#define OCAP   512                     // owner-list cap per row

// item = row(12)<<14 | col(12)<<2 | t(2);  bin = item>>16 (row>>2)

__device__ __forceinline__ float wred(float v) {
    #pragma unroll
    for (int off = 32; off > 0; off >>= 1) v += __shfl_down(v, off);
    return v;
}

// ---- k_bin: deterministic per-block binning, zero global atomics ------------
__global__ __launch_bounds__(256) void k_bin(const int* __restrict__ el,
                                             unsigned short* __restrict__ runstart,
                                             unsigned int* __restrict__ bigbin,
                                             const float* __restrict__ inputs,
                                             const float* __restrict__ lin_w,
                                             const float* __restrict__ lin_b,
                                             float* __restrict__ s0) {
    __shared__ unsigned int cnt[NBINS], pref[NBINS];
    __shared__ unsigned int items[IPB];            // 6 KB
    __shared__ unsigned int wtot[4], wo[4];
    int tid = threadIdx.x, bid = blockIdx.x;
    int lane = tid & 63, wid = tid >> 6;

    #pragma unroll
    for (int j = 0; j < 4; j++) cnt[4 * tid + j] = 0u;
    __syncthreads();

    unsigned int it[6];
    #pragma unroll
    for (int k = 0; k < 3; k++) {                  // 3 edges -> 6 directed items
        int edge = bid * EPB + k * 256 + tid;
        int t = edge >> 17;                        // EE = 2^17
        int e = edge & (EE - 1);
        unsigned int a = (unsigned int)el[(t * 2) * EE + e];
        unsigned int b = (unsigned int)el[(t * 2 + 1) * EE + e];
        it[2 * k]     = (a << 14) | (b << 2) | (unsigned int)t;
        it[2 * k + 1] = (b << 14) | (a << 2) | (unsigned int)t;
        atomicAdd(&cnt[a >> 2], 1u);
        atomicAdd(&cnt[b >> 2], 1u);
    }
    __syncthreads();

    unsigned int c0 = cnt[4 * tid], c1 = cnt[4 * tid + 1];
    unsigned int c2 = cnt[4 * tid + 2], c3 = cnt[4 * tid + 3];
    unsigned int s = c0 + c1 + c2 + c3, p = s;
    #pragma unroll
    for (int off = 1; off < 64; off <<= 1) {
        unsigned int v = __shfl_up(p, off);
        if (lane >= off) p += v;
    }
    if (lane == 63) wtot[wid] = p;
    __syncthreads();
    if (tid == 0) { unsigned int r = 0;
        #pragma unroll
        for (int q = 0; q < 4; q++) { wo[q] = r; r += wtot[q]; } }
    __syncthreads();
    unsigned int ex = wo[wid] + (p - s);
    pref[4 * tid]     = ex;
    pref[4 * tid + 1] = ex + c0;
    pref[4 * tid + 2] = ex + c0 + c1;
    pref[4 * tid + 3] = ex + c0 + c1 + c2;
    runstart[bid * NBINS + 4 * tid]     = (unsigned short)ex;       // coalesced 8B
    runstart[bid * NBINS + 4 * tid + 1] = (unsigned short)(ex + c0);
    runstart[bid * NBINS + 4 * tid + 2] = (unsigned short)(ex + c0 + c1);
    runstart[bid * NBINS + 4 * tid + 3] = (unsigned short)(ex + c0 + c1 + c2);
    __syncthreads();
    #pragma unroll
    for (int j = 0; j < 4; j++) cnt[4 * tid + j] = 0u;  // reuse as rank counters
    __syncthreads();

    #pragma unroll
    for (int k = 0; k < 6; k++) {
        unsigned int v = it[k], bin = v >> 16;
        unsigned int r = atomicAdd(&cnt[bin], 1u);
        items[pref[bin] + r] = v;
    }
    __syncthreads();

    #pragma unroll
    for (int k = 0; k < 6; k++)                    // fully coalesced flush
        bigbin[bid * IPB + k * 256 + tid] = items[k * 256 + tid];

    // fused: s0 = inputs @ lin_w.T + lin_b  (2048 waves x 2 rows)
    #pragma unroll
    for (int r = 0; r < 2; r++) {
        int row = (bid * 4 + wid) * 2 + r;
        const float* rp = inputs + row * ADIM;
        float v = rp[lane] * lin_w[lane] + rp[lane + 64] * lin_w[lane + 64];
        #pragma unroll
        for (int off = 32; off > 0; off >>= 1) v += __shfl_down(v, off);
        if (lane == 0) s0[row] = v + lin_b[0];
    }
}

// ---- k_l0: one telescoping pass; REGISTER accumulation (no accf atomics) ----
__global__ __launch_bounds__(256) void k_l0(const unsigned short* __restrict__ runstart,
                                            const unsigned int* __restrict__ bigbin,
                                            unsigned int* __restrict__ cnt2,
                                            unsigned short* __restrict__ entries2,
                                            const float* __restrict__ s_in,
                                            const float* __restrict__ att_w,
                                            const float* __restrict__ edge_emb,
                                            float* __restrict__ s_out) {
    __shared__ unsigned int mask[RPB2][512];       // 8 KB nibble-mask
    __shared__ unsigned short ownerc[RPB2][OCAP];  // 4 KB owner cols
    __shared__ unsigned int rcnt[RPB2];
    __shared__ float accw[4][16];                  // per-wave partials
    __shared__ float accT[16];
    __shared__ float lut0[8], lut1[8], wc4[4], Sred[4], arow[RPB2][2];
    int tid = threadIdx.x, bid = blockIdx.x;
    int lane = tid & 63, wid = tid >> 6;

    if (tid < 16) {                                // layer 0 constants
        int h = tid >> 3, m = tid & 7;
        const float* w = att_w + h * (DD + 2);
        float e0 = 0.f, e1 = 0.f, e2 = 0.f;
        #pragma unroll
        for (int d = 0; d < DD; d++) {
            float wd = w[1 + d];
            e0 += edge_emb[0 * DD + d] * wd;
            e1 += edge_emb[1 * DD + d] * wd;
            e2 += edge_emb[2 * DD + d] * wd;
        }
        float l = (m & 1 ? e0 : 0.f) + (m & 2 ? e1 : 0.f) + (m & 4 ? e2 : 0.f);
        if (h) lut1[m] = l; else lut0[m] = l;
        if (m == 0) { wc4[h] = w[0]; wc4[2 + h] = w[DD + 1]; }
    }
    if (tid < RPB2) rcnt[tid] = 0u;
    #pragma unroll
    for (int i = 0; i < 8; i++)                    // zero 8 KB mask
        ((unsigned int*)mask)[i * 256 + tid] = 0u;

    float ps = 0.f;                                // S = sum(s_in)
    #pragma unroll
    for (int i = 0; i < 16; i++) ps += s_in[i * 256 + tid];
    #pragma unroll
    for (int off = 32; off > 0; off >>= 1) ps += __shfl_down(ps, off);
    if (lane == 0) Sred[wid] = ps;
    __syncthreads();
    float S = Sred[0] + Sred[1] + Sred[2] + Sred[3];
    if (tid < RPB2) {                              // per-row a-terms
        float si = s_in[bid * RPB2 + tid];
        arow[tid][0] = wc4[0] * si;
        arow[tid][1] = wc4[1] * si;
    }
    __syncthreads();                               // mask/arow ready

    // 16 register accumulators: n<h><row>, d<h><row>
    float n00 = 0.f, d00 = 0.f, n10 = 0.f, d10 = 0.f;
    float n01 = 0.f, d01 = 0.f, n11 = 0.f, d11 = 0.f;
    float n02 = 0.f, d02 = 0.f, n12 = 0.f, d12 = 0.f;
    float n03 = 0.f, d03 = 0.f, n13 = 0.f, d13 = 0.f;

    float b0 = wc4[2], b1 = wc4[3];
    #pragma unroll
    for (int q = 0; q < 2; q++) {                  // one pass over this bin's runs
        int blk = q * 256 + tid;
        unsigned int st = runstart[blk * NBINS + bid];
        unsigned int en = (bid == NBINS - 1) ? (unsigned int)IPB
                                             : runstart[blk * NBINS + bid + 1];
        const unsigned int* src = bigbin + (size_t)blk * IPB;
        for (unsigned int j = st; j < en; j++) {
            unsigned int v = src[j];
            unsigned int lr = (v >> 14) & 3u;
            unsigned int col = (v >> 2) & 0xFFFu;
            unsigned int t = v & 3u;
            unsigned int sh = (col & 7u) << 2;
            unsigned int bit = 1u << (sh + t);
            unsigned int old = atomicOr(&mask[lr][col >> 3], bit);
            if (old & bit) continue;               // duplicate (pair,type)
            unsigned int oldnib = (old >> sh) & 0xFu;
            unsigned int newnib = oldnib | (1u << t);
            float sj = s_in[col];
            float a0 = arow[lr][0], a1 = arow[lr][1];
            float cn = (float)__popc(newnib);
            float l0n = cn * (a0 + b0 * sj) + lut0[newnib];
            l0n = (l0n > 0.f) ? l0n : NEG * l0n;
            float x0 = __expf(l0n) - 1.0f;
            float l1n = cn * (a1 + b1 * sj) + lut1[newnib];
            l1n = (l1n > 0.f) ? l1n : NEG * l1n;
            float x1 = __expf(l1n) - 1.0f;
            if (oldnib) {                          // rare: subtract f(old)
                float co = (float)__popc(oldnib);
                float l0o = co * (a0 + b0 * sj) + lut0[oldnib];
                l0o = (l0o > 0.f) ? l0o : NEG * l0o;
                x0 -= __expf(l0o) - 1.0f;
                float l1o = co * (a1 + b1 * sj) + lut1[oldnib];
                l1o = (l1o > 0.f) ? l1o : NEG * l1o;
                x1 -= __expf(l1o) - 1.0f;
            } else {                               // first bit: owner append
                unsigned int r = atomicAdd(&rcnt[lr], 1u);
                if (r < OCAP) ownerc[lr][r] = (unsigned short)col;
            }
            float v0 = x0 * sj, v1 = x1 * sj;
            if (lr == 0)      { n00 += v0; d00 += x0; n10 += v1; d10 += x1; }
            else if (lr == 1) { n01 += v0; d01 += x0; n11 += v1; d11 += x1; }
            else if (lr == 2) { n02 += v0; d02 += x0; n12 += v1; d12 += x1; }
            else              { n03 += v0; d03 += x0; n13 += v1; d13 += x1; }
        }
    }

    // wave-reduce the 16 accumulators (uniform control flow)
    n00 = wred(n00); d00 = wred(d00); n10 = wred(n10); d10 = wred(d10);
    n01 = wred(n01); d01 = wred(d01); n11 = wred(n11); d11 = wred(d11);
    n02 = wred(n02); d02 = wred(d02); n12 = wred(n12); d12 = wred(d12);
    n03 = wred(n03); d03 = wred(d03); n13 = wred(n13); d13 = wred(d13);
    if (lane == 0) {
        float* aw = accw[wid];
        aw[0]  = n00; aw[1]  = d00; aw[2]  = n10; aw[3]  = d10;
        aw[4]  = n01; aw[5]  = d01; aw[6]  = n11; aw[7]  = d11;
        aw[8]  = n02; aw[9]  = d02; aw[10] = n12; aw[11] = d12;
        aw[12] = n03; aw[13] = d03; aw[14] = n13; aw[15] = d13;
    }
    __syncthreads();
    if (tid < 16)                                  // deterministic cross-wave sum
        accT[tid] = accw[0][tid] + accw[1][tid] + accw[2][tid] + accw[3][tid];
    __syncthreads();

    // fixup: read final nibbles, emit CSR coalesced
    #pragma unroll
    for (int lr = 0; lr < RPB2; lr++) {
        int row = bid * RPB2 + lr;
        unsigned int n = min(rcnt[lr], (unsigned int)OCAP);
        for (unsigned int i = tid; i < n; i += 256) {
            unsigned int col = ownerc[lr][i];
            unsigned int nib = (mask[lr][col >> 3] >> ((col & 7u) << 2)) & 0xFu;
            entries2[(size_t)row * CAP + i] = (unsigned short)(col | (nib << 12));
        }
    }
    if (tid < RPB2) {
        int row = bid * RPB2 + tid;
        float o0 = (S + accT[tid * 4 + 0]) / ((float)NN + accT[tid * 4 + 1]);
        float o1 = (S + accT[tid * 4 + 2]) / ((float)NN + accT[tid * 4 + 3]);
        s_out[row] = 0.5f * (o0 + o1);
        cnt2[row] = min(rcnt[tid], (unsigned int)CAP);
    }
}

// ---- k_l1: layer 1 over compact CSR (row per wave) --------------------------
__global__ __launch_bounds__(256) void k_l1(const unsigned int* __restrict__ cnt2,
                                            const unsigned short* __restrict__ entries2,
                                            const float* __restrict__ s_in,
                                            const float* __restrict__ att_w,
                                            const float* __restrict__ edge_emb,
                                            float* __restrict__ s_out) {
    __shared__ float lut0[8], lut1[8], wc4[4], Sred[4];
    int tid = threadIdx.x;

    if (tid < 16) {                                // layer 1 constants
        int h = tid >> 3, m = tid & 7;
        const float* w = att_w + (2 + h) * (DD + 2);
        float e0 = 0.f, e1 = 0.f, e2 = 0.f;
        #pragma unroll
        for (int d = 0; d < DD; d++) {
            float wd = w[1 + d];
            e0 += edge_emb[0 * DD + d] * wd;
            e1 += edge_emb[1 * DD + d] * wd;
            e2 += edge_emb[2 * DD + d] * wd;
        }
        float l = (m & 1 ? e0 : 0.f) + (m & 2 ? e1 : 0.f) + (m & 4 ? e2 : 0.f);
        if (h) lut1[m] = l; else lut0[m] = l;
        if (m == 0) { wc4[h] = w[0]; wc4[2 + h] = w[DD + 1]; }
    }

    float ps = 0.f;
    for (int j = tid; j < NN; j += 256) ps += s_in[j];
    #pragma unroll
    for (int off = 32; off > 0; off >>= 1) ps += __shfl_down(ps, off);
    int wid = tid >> 6, lane = tid & 63;
    if (lane == 0) Sred[wid] = ps;
    __syncthreads();
    float S = Sred[0] + Sred[1] + Sred[2] + Sred[3];

    int row = blockIdx.x * 4 + wid;
    float si = s_in[row];
    float a0 = wc4[0] * si, a1 = wc4[1] * si;
    float b0 = wc4[2],      b1 = wc4[3];
    unsigned int n = cnt2[row];
    const unsigned short* ent = entries2 + (size_t)row * CAP;

    float num0 = 0.f, den0 = 0.f, num1 = 0.f, den1 = 0.f;
    for (unsigned int i = lane; i < n; i += 64) {
        unsigned int v = ent[i];
        unsigned int j = v & 0xFFFu, nib = v >> 12;
        float c  = (float)__popc(nib);
        float sj = s_in[j];
        float l0 = c * (a0 + b0 * sj) + lut0[nib];
        l0 = (l0 > 0.f) ? l0 : NEG * l0;
        float x0 = __expf(l0) - 1.0f;
        num0 += x0 * sj; den0 += x0;
        float l1 = c * (a1 + b1 * sj) + lut1[nib];
        l1 = (l1 > 0.f) ? l1 : NEG * l1;
        float x1 = __expf(l1) - 1.0f;
        num1 += x1 * sj; den1 += x1;
    }

    #pragma unroll
    for (int off = 32; off > 0; off >>= 1) {
        num0 += __shfl_down(num0, off); den0 += __shfl_down(den0, off);
        num1 += __shfl_down(num1, off); den1 += __shfl_down(den1, off);
    }
    if (lane == 0) {
        float o0 = (S + num0) / ((float)NN + den0);
        float o1 = (S + num1) / ((float)NN + den1);
        s_out[row] = 0.5f * (o0 + o1);
    }
}

// ---- host-side launcher ------------------------------------------------------
// MEASUREMENT ROUND: two duplicate k_l1 dispatches into a scratch output.
// Output byte-identical to R22; dur delta = 2 x cost(k_l1).
extern "C" void kernel_launch(void* const* d_in, const int* in_sizes, int n_in,
                              void* d_out, int out_size, void* d_ws, size_t ws_size,
                              hipStream_t stream) {
    const float* inputs   = (const float*)d_in[0];
    const float* lin_w    = (const float*)d_in[1];
    const float* lin_b    = (const float*)d_in[2];
    const float* edge_emb = (const float*)d_in[3];
    const float* att_w    = (const float*)d_in[4];
    const int*   el       = (const int*)d_in[5];
    float* out = (float*)d_out;

    char* ws = (char*)d_ws;
    unsigned short* runstart = (unsigned short*)ws;                       // 1 MB
    unsigned int*   bigbin   = (unsigned int*)(ws + 1048576);             // 3 MB
    unsigned short* entries2 = (unsigned short*)(ws + 4194304);           // 4 MB
    unsigned int*   cnt2     = (unsigned int*)(ws + 8388608);             // 16 KB
    float*          s0       = (float*)(ws + 8404992);                    // 16 KB
    float*          s1       = (float*)(ws + 8421376);                    // 16 KB
    float*          s1c      = (float*)(ws + 8437760);                    // 16 KB scratch

    k_bin<<<NBB, 256, 0, stream>>>(el, runstart, bigbin, inputs, lin_w, lin_b, s0);
    k_l0 <<<NBINS, 256, 0, stream>>>(runstart, bigbin, cnt2, entries2,
                                     s0, att_w, edge_emb, s1);
    // duplicates (scratch output; measure k_l1 via dur delta)
    k_l1 <<<1024, 256, 0, stream>>>(cnt2, entries2, s1, att_w, edge_emb, s1c);
    k_l1 <<<1024, 256, 0, stream>>>(cnt2, entries2, s1, att_w, edge_emb, s1c);
    k_l1 <<<1024, 256, 0, stream>>>(cnt2, entries2, s1, att_w, edge_emb, out);
}

// Round 24
// 46.266 us; speedup vs baseline: 1.1839x; 1.1839x over previous
//
#include <hip/hip_runtime.h>

#define NN     4096
#define TT     3
#define DD     20
#define EE     131072
#define ADIM   128
#define NEG    0.2f
#define NEDGE  (TT * EE)               // 393216 edges
#define NBINS  1024                    // row>>2 -> 4 rows per bin
#define RPB2   4
#define NBB    512                     // k_bin blocks
#define EPB    (NEDGE / NBB)           // 768 edges per block -> 1536 items exact
#define IPB    (2 * EPB)               // 1536
#define CAP    512                     // CSR entries per row (max ~260)
#define OCAP   512                     // owner-list cap per row

// item = row(12)<<14 | col(12)<<2 | t(2);  bin = item>>16 (row>>2)
// runstartT layout: [bin][blk]  (transposed -> coalesced reads in k_l0)

__device__ __forceinline__ float wred(float v) {
    #pragma unroll
    for (int off = 32; off > 0; off >>= 1) v += __shfl_down(v, off);
    return v;
}

// ---- k_bin: deterministic per-block binning, zero global atomics ------------
__global__ __launch_bounds__(256) void k_bin(const int* __restrict__ el,
                                             unsigned short* __restrict__ rsT,
                                             unsigned int* __restrict__ bigbin,
                                             const float* __restrict__ inputs,
                                             const float* __restrict__ lin_w,
                                             const float* __restrict__ lin_b,
                                             float* __restrict__ s0) {
    __shared__ unsigned int cnt[NBINS], pref[NBINS];
    __shared__ unsigned int items[IPB];            // 6 KB
    __shared__ unsigned int wtot[4], wo[4];
    int tid = threadIdx.x, bid = blockIdx.x;
    int lane = tid & 63, wid = tid >> 6;

    #pragma unroll
    for (int j = 0; j < 4; j++) cnt[4 * tid + j] = 0u;
    __syncthreads();

    unsigned int it[6];
    #pragma unroll
    for (int k = 0; k < 3; k++) {                  // 3 edges -> 6 directed items
        int edge = bid * EPB + k * 256 + tid;
        int t = edge >> 17;                        // EE = 2^17
        int e = edge & (EE - 1);
        unsigned int a = (unsigned int)el[(t * 2) * EE + e];
        unsigned int b = (unsigned int)el[(t * 2 + 1) * EE + e];
        it[2 * k]     = (a << 14) | (b << 2) | (unsigned int)t;
        it[2 * k + 1] = (b << 14) | (a << 2) | (unsigned int)t;
        atomicAdd(&cnt[a >> 2], 1u);
        atomicAdd(&cnt[b >> 2], 1u);
    }
    __syncthreads();

    unsigned int c0 = cnt[4 * tid], c1 = cnt[4 * tid + 1];
    unsigned int c2 = cnt[4 * tid + 2], c3 = cnt[4 * tid + 3];
    unsigned int s = c0 + c1 + c2 + c3, p = s;
    #pragma unroll
    for (int off = 1; off < 64; off <<= 1) {
        unsigned int v = __shfl_up(p, off);
        if (lane >= off) p += v;
    }
    if (lane == 63) wtot[wid] = p;
    __syncthreads();
    if (tid == 0) { unsigned int r = 0;
        #pragma unroll
        for (int q = 0; q < 4; q++) { wo[q] = r; r += wtot[q]; } }
    __syncthreads();
    unsigned int ex = wo[wid] + (p - s);
    pref[4 * tid]     = ex;
    pref[4 * tid + 1] = ex + c0;
    pref[4 * tid + 2] = ex + c0 + c1;
    pref[4 * tid + 3] = ex + c0 + c1 + c2;
    // transposed boundary table (scattered 2B stores, fire-and-forget)
    rsT[(size_t)(4 * tid + 0) * NBB + bid] = (unsigned short)ex;
    rsT[(size_t)(4 * tid + 1) * NBB + bid] = (unsigned short)(ex + c0);
    rsT[(size_t)(4 * tid + 2) * NBB + bid] = (unsigned short)(ex + c0 + c1);
    rsT[(size_t)(4 * tid + 3) * NBB + bid] = (unsigned short)(ex + c0 + c1 + c2);
    __syncthreads();
    #pragma unroll
    for (int j = 0; j < 4; j++) cnt[4 * tid + j] = 0u;  // reuse as rank counters
    __syncthreads();

    #pragma unroll
    for (int k = 0; k < 6; k++) {
        unsigned int v = it[k], bin = v >> 16;
        unsigned int r = atomicAdd(&cnt[bin], 1u);
        items[pref[bin] + r] = v;
    }
    __syncthreads();

    #pragma unroll
    for (int k = 0; k < 6; k++)                    // fully coalesced flush
        bigbin[bid * IPB + k * 256 + tid] = items[k * 256 + tid];

    // fused: s0 = inputs @ lin_w.T + lin_b  (2048 waves x 2 rows)
    #pragma unroll
    for (int r = 0; r < 2; r++) {
        int row = (bid * 4 + wid) * 2 + r;
        const float* rp = inputs + row * ADIM;
        float v = rp[lane] * lin_w[lane] + rp[lane + 64] * lin_w[lane + 64];
        #pragma unroll
        for (int off = 32; off > 0; off >>= 1) v += __shfl_down(v, off);
        if (lane == 0) s0[row] = v + lin_b[0];
    }
}

// ---- k_l0: telescoping pass, coalesced boundaries, dual-run interleave ------
__global__ __launch_bounds__(256) void k_l0(const unsigned short* __restrict__ rsT,
                                            const unsigned int* __restrict__ bigbin,
                                            unsigned int* __restrict__ cnt2,
                                            unsigned short* __restrict__ entries2,
                                            const float* __restrict__ s_in,
                                            const float* __restrict__ att_w,
                                            const float* __restrict__ edge_emb,
                                            float* __restrict__ s_out) {
    __shared__ unsigned int mask[RPB2][512];       // 8 KB nibble-mask
    __shared__ unsigned short ownerc[RPB2][OCAP];  // 4 KB owner cols
    __shared__ unsigned int rcnt[RPB2];
    __shared__ float accw[4][16];                  // per-wave partials
    __shared__ float accT[16];
    __shared__ float lut0[8], lut1[8], wc4[4], Sred[4], arow[RPB2][2];
    int tid = threadIdx.x, bid = blockIdx.x;
    int lane = tid & 63, wid = tid >> 6;

    if (tid < 16) {                                // layer 0 constants
        int h = tid >> 3, m = tid & 7;
        const float* w = att_w + h * (DD + 2);
        float e0 = 0.f, e1 = 0.f, e2 = 0.f;
        #pragma unroll
        for (int d = 0; d < DD; d++) {
            float wd = w[1 + d];
            e0 += edge_emb[0 * DD + d] * wd;
            e1 += edge_emb[1 * DD + d] * wd;
            e2 += edge_emb[2 * DD + d] * wd;
        }
        float l = (m & 1 ? e0 : 0.f) + (m & 2 ? e1 : 0.f) + (m & 4 ? e2 : 0.f);
        if (h) lut1[m] = l; else lut0[m] = l;
        if (m == 0) { wc4[h] = w[0]; wc4[2 + h] = w[DD + 1]; }
    }
    if (tid < RPB2) rcnt[tid] = 0u;
    #pragma unroll
    for (int i = 0; i < 8; i++)                    // zero 8 KB mask
        ((unsigned int*)mask)[i * 256 + tid] = 0u;

    float ps = 0.f;                                // S = sum(s_in)
    #pragma unroll
    for (int i = 0; i < 16; i++) ps += s_in[i * 256 + tid];
    #pragma unroll
    for (int off = 32; off > 0; off >>= 1) ps += __shfl_down(ps, off);
    if (lane == 0) Sred[wid] = ps;
    __syncthreads();
    float S = Sred[0] + Sred[1] + Sred[2] + Sred[3];
    if (tid < RPB2) {                              // per-row a-terms
        float si = s_in[bid * RPB2 + tid];
        arow[tid][0] = wc4[0] * si;
        arow[tid][1] = wc4[1] * si;
    }
    __syncthreads();                               // mask/arow ready

    // 16 register accumulators: n<h><row>, d<h><row>
    float n00 = 0.f, d00 = 0.f, n10 = 0.f, d10 = 0.f;
    float n01 = 0.f, d01 = 0.f, n11 = 0.f, d11 = 0.f;
    float n02 = 0.f, d02 = 0.f, n12 = 0.f, d12 = 0.f;
    float n03 = 0.f, d03 = 0.f, n13 = 0.f, d13 = 0.f;
    float b0 = wc4[2], b1 = wc4[3];

#define PROCESS(vv)                                                            \
    do {                                                                       \
        unsigned int lr = ((vv) >> 14) & 3u;                                   \
        unsigned int col = ((vv) >> 2) & 0xFFFu;                               \
        unsigned int t = (vv) & 3u;                                            \
        unsigned int sh = (col & 7u) << 2;                                     \
        unsigned int bit = 1u << (sh + t);                                     \
        unsigned int old = atomicOr(&mask[lr][col >> 3], bit);                 \
        if (!(old & bit)) {                                                    \
            unsigned int oldnib = (old >> sh) & 0xFu;                          \
            unsigned int newnib = oldnib | (1u << t);                          \
            float sj = s_in[col];                                              \
            float a0 = arow[lr][0], a1 = arow[lr][1];                          \
            float cn = (float)__popc(newnib);                                  \
            float l0n = cn * (a0 + b0 * sj) + lut0[newnib];                    \
            l0n = (l0n > 0.f) ? l0n : NEG * l0n;                               \
            float x0 = __expf(l0n) - 1.0f;                                     \
            float l1n = cn * (a1 + b1 * sj) + lut1[newnib];                    \
            l1n = (l1n > 0.f) ? l1n : NEG * l1n;                               \
            float x1 = __expf(l1n) - 1.0f;                                     \
            if (oldnib) {                                                      \
                float co = (float)__popc(oldnib);                              \
                float l0o = co * (a0 + b0 * sj) + lut0[oldnib];                \
                l0o = (l0o > 0.f) ? l0o : NEG * l0o;                           \
                x0 -= __expf(l0o) - 1.0f;                                      \
                float l1o = co * (a1 + b1 * sj) + lut1[oldnib];                \
                l1o = (l1o > 0.f) ? l1o : NEG * l1o;                           \
                x1 -= __expf(l1o) - 1.0f;                                      \
            } else {                                                           \
                unsigned int r = atomicAdd(&rcnt[lr], 1u);                     \
                if (r < OCAP) ownerc[lr][r] = (unsigned short)col;             \
            }                                                                  \
            float v0f = x0 * sj, v1f = x1 * sj;                                \
            if (lr == 0)      { n00 += v0f; d00 += x0; n10 += v1f; d10 += x1; }\
            else if (lr == 1) { n01 += v0f; d01 += x0; n11 += v1f; d11 += x1; }\
            else if (lr == 2) { n02 += v0f; d02 += x0; n12 += v1f; d12 += x1; }\
            else              { n03 += v0f; d03 += x0; n13 += v1f; d13 += x1; }\
        }                                                                      \
    } while (0)

    // coalesced boundary reads (transposed layout), dual-run interleaved walk
    unsigned int st0 = rsT[(size_t)bid * NBB + tid];
    unsigned int st1 = rsT[(size_t)bid * NBB + 256 + tid];
    unsigned int en0, en1;
    if (bid == NBINS - 1) { en0 = IPB; en1 = IPB; }
    else {
        en0 = rsT[(size_t)(bid + 1) * NBB + tid];
        en1 = rsT[(size_t)(bid + 1) * NBB + 256 + tid];
    }
    const unsigned int* src0 = bigbin + (size_t)tid * IPB;
    const unsigned int* src1 = bigbin + (size_t)(256 + tid) * IPB;

    while (st0 < en0 && st1 < en1) {               // MLP-2 main loop
        unsigned int v0 = src0[st0];
        unsigned int v1 = src1[st1];
        PROCESS(v0);
        PROCESS(v1);
        ++st0; ++st1;
    }
    while (st0 < en0) { unsigned int v0 = src0[st0++]; PROCESS(v0); }
    while (st1 < en1) { unsigned int v1 = src1[st1++]; PROCESS(v1); }
#undef PROCESS

    // wave-reduce the 16 accumulators (uniform control flow)
    n00 = wred(n00); d00 = wred(d00); n10 = wred(n10); d10 = wred(d10);
    n01 = wred(n01); d01 = wred(d01); n11 = wred(n11); d11 = wred(d11);
    n02 = wred(n02); d02 = wred(d02); n12 = wred(n12); d12 = wred(d12);
    n03 = wred(n03); d03 = wred(d03); n13 = wred(n13); d13 = wred(d13);
    if (lane == 0) {
        float* aw = accw[wid];
        aw[0]  = n00; aw[1]  = d00; aw[2]  = n10; aw[3]  = d10;
        aw[4]  = n01; aw[5]  = d01; aw[6]  = n11; aw[7]  = d11;
        aw[8]  = n02; aw[9]  = d02; aw[10] = n12; aw[11] = d12;
        aw[12] = n03; aw[13] = d03; aw[14] = n13; aw[15] = d13;
    }
    __syncthreads();
    if (tid < 16)                                  // deterministic cross-wave sum
        accT[tid] = accw[0][tid] + accw[1][tid] + accw[2][tid] + accw[3][tid];
    __syncthreads();

    // fixup: read final nibbles, emit CSR coalesced
    #pragma unroll
    for (int lr = 0; lr < RPB2; lr++) {
        int row = bid * RPB2 + lr;
        unsigned int n = min(rcnt[lr], (unsigned int)OCAP);
        for (unsigned int i = tid; i < n; i += 256) {
            unsigned int col = ownerc[lr][i];
            unsigned int nib = (mask[lr][col >> 3] >> ((col & 7u) << 2)) & 0xFu;
            entries2[(size_t)row * CAP + i] = (unsigned short)(col | (nib << 12));
        }
    }
    if (tid < RPB2) {
        int row = bid * RPB2 + tid;
        float o0 = (S + accT[tid * 4 + 0]) / ((float)NN + accT[tid * 4 + 1]);
        float o1 = (S + accT[tid * 4 + 2]) / ((float)NN + accT[tid * 4 + 3]);
        s_out[row] = 0.5f * (o0 + o1);
        cnt2[row] = min(rcnt[tid], (unsigned int)CAP);
    }
}

// ---- k_l1: layer 1 over compact CSR (row per wave) --------------------------
__global__ __launch_bounds__(256) void k_l1(const unsigned int* __restrict__ cnt2,
                                            const unsigned short* __restrict__ entries2,
                                            const float* __restrict__ s_in,
                                            const float* __restrict__ att_w,
                                            const float* __restrict__ edge_emb,
                                            float* __restrict__ s_out) {
    __shared__ float lut0[8], lut1[8], wc4[4], Sred[4];
    int tid = threadIdx.x;

    if (tid < 16) {                                // layer 1 constants
        int h = tid >> 3, m = tid & 7;
        const float* w = att_w + (2 + h) * (DD + 2);
        float e0 = 0.f, e1 = 0.f, e2 = 0.f;
        #pragma unroll
        for (int d = 0; d < DD; d++) {
            float wd = w[1 + d];
            e0 += edge_emb[0 * DD + d] * wd;
            e1 += edge_emb[1 * DD + d] * wd;
            e2 += edge_emb[2 * DD + d] * wd;
        }
        float l = (m & 1 ? e0 : 0.f) + (m & 2 ? e1 : 0.f) + (m & 4 ? e2 : 0.f);
        if (h) lut1[m] = l; else lut0[m] = l;
        if (m == 0) { wc4[h] = w[0]; wc4[2 + h] = w[DD + 1]; }
    }

    float ps = 0.f;
    for (int j = tid; j < NN; j += 256) ps += s_in[j];
    #pragma unroll
    for (int off = 32; off > 0; off >>= 1) ps += __shfl_down(ps, off);
    int wid = tid >> 6, lane = tid & 63;
    if (lane == 0) Sred[wid] = ps;
    __syncthreads();
    float S = Sred[0] + Sred[1] + Sred[2] + Sred[3];

    int row = blockIdx.x * 4 + wid;
    float si = s_in[row];
    float a0 = wc4[0] * si, a1 = wc4[1] * si;
    float b0 = wc4[2],      b1 = wc4[3];
    unsigned int n = cnt2[row];
    const unsigned short* ent = entries2 + (size_t)row * CAP;

    float num0 = 0.f, den0 = 0.f, num1 = 0.f, den1 = 0.f;
    for (unsigned int i = lane; i < n; i += 64) {
        unsigned int v = ent[i];
        unsigned int j = v & 0xFFFu, nib = v >> 12;
        float c  = (float)__popc(nib);
        float sj = s_in[j];
        float l0 = c * (a0 + b0 * sj) + lut0[nib];
        l0 = (l0 > 0.f) ? l0 : NEG * l0;
        float x0 = __expf(l0) - 1.0f;
        num0 += x0 * sj; den0 += x0;
        float l1 = c * (a1 + b1 * sj) + lut1[nib];
        l1 = (l1 > 0.f) ? l1 : NEG * l1;
        float x1 = __expf(l1) - 1.0f;
        num1 += x1 * sj; den1 += x1;
    }

    #pragma unroll
    for (int off = 32; off > 0; off >>= 1) {
        num0 += __shfl_down(num0, off); den0 += __shfl_down(den0, off);
        num1 += __shfl_down(num1, off); den1 += __shfl_down(den1, off);
    }
    if (lane == 0) {
        float o0 = (S + num0) / ((float)NN + den0);
        float o1 = (S + num1) / ((float)NN + den1);
        s_out[row] = 0.5f * (o0 + o1);
    }
}

// ---- host-side launcher ------------------------------------------------------
extern "C" void kernel_launch(void* const* d_in, const int* in_sizes, int n_in,
                              void* d_out, int out_size, void* d_ws, size_t ws_size,
                              hipStream_t stream) {
    const float* inputs   = (const float*)d_in[0];
    const float* lin_w    = (const float*)d_in[1];
    const float* lin_b    = (const float*)d_in[2];
    const float* edge_emb = (const float*)d_in[3];
    const float* att_w    = (const float*)d_in[4];
    const int*   el       = (const int*)d_in[5];
    float* out = (float*)d_out;

    char* ws = (char*)d_ws;
    unsigned short* rsT      = (unsigned short*)ws;                       // 1 MB
    unsigned int*   bigbin   = (unsigned int*)(ws + 1048576);             // 3 MB
    unsigned short* entries2 = (unsigned short*)(ws + 4194304);           // 4 MB
    unsigned int*   cnt2     = (unsigned int*)(ws + 8388608);             // 16 KB
    float*          s0       = (float*)(ws + 8404992);                    // 16 KB
    float*          s1       = (float*)(ws + 8421376);                    // 16 KB

    k_bin<<<NBB, 256, 0, stream>>>(el, rsT, bigbin, inputs, lin_w, lin_b, s0);
    k_l0 <<<NBINS, 256, 0, stream>>>(rsT, bigbin, cnt2, entries2,
                                     s0, att_w, edge_emb, s1);
    k_l1 <<<1024, 256, 0, stream>>>(cnt2, entries2, s1, att_w, edge_emb, out);
}

// Round 25
// 38.973 us; speedup vs baseline: 1.4054x; 1.1871x over previous
//
#include <hip/hip_runtime.h>

#define NN     4096
#define TT     3
#define DD     20
#define EE     131072
#define ADIM   128
#define NEG    0.2f
#define NEDGE  (TT * EE)               // 393216 edges
#define NBINS  1024                    // row>>2 -> 4 rows per bin
#define RPB2   4
#define NBB    512                     // k_bin blocks
#define EPB    (NEDGE / NBB)           // 768 edges per block -> 1536 items exact
#define IPB    (2 * EPB)               // 1536
#define CAP    512                     // CSR entries per row (max ~260)
#define OCAP   512                     // owner-list cap per row
#define FCAP   2048                    // flat per-bin item cap (mean 768)

// item = row(12)<<14 | col(12)<<2 | t(2);  bin = item>>16 (row>>2)

__device__ __forceinline__ float wred(float v) {
    #pragma unroll
    for (int off = 32; off > 0; off >>= 1) v += __shfl_down(v, off);
    return v;
}

// ---- k_bin: deterministic per-block binning, zero global atomics (R22) ------
__global__ __launch_bounds__(256) void k_bin(const int* __restrict__ el,
                                             unsigned short* __restrict__ runstart,
                                             unsigned int* __restrict__ bigbin,
                                             const float* __restrict__ inputs,
                                             const float* __restrict__ lin_w,
                                             const float* __restrict__ lin_b,
                                             float* __restrict__ s0) {
    __shared__ unsigned int cnt[NBINS], pref[NBINS];
    __shared__ unsigned int items[IPB];            // 6 KB
    __shared__ unsigned int wtot[4], wo[4];
    int tid = threadIdx.x, bid = blockIdx.x;
    int lane = tid & 63, wid = tid >> 6;

    #pragma unroll
    for (int j = 0; j < 4; j++) cnt[4 * tid + j] = 0u;
    __syncthreads();

    unsigned int it[6];
    #pragma unroll
    for (int k = 0; k < 3; k++) {                  // 3 edges -> 6 directed items
        int edge = bid * EPB + k * 256 + tid;
        int t = edge >> 17;                        // EE = 2^17
        int e = edge & (EE - 1);
        unsigned int a = (unsigned int)el[(t * 2) * EE + e];
        unsigned int b = (unsigned int)el[(t * 2 + 1) * EE + e];
        it[2 * k]     = (a << 14) | (b << 2) | (unsigned int)t;
        it[2 * k + 1] = (b << 14) | (a << 2) | (unsigned int)t;
        atomicAdd(&cnt[a >> 2], 1u);
        atomicAdd(&cnt[b >> 2], 1u);
    }
    __syncthreads();

    unsigned int c0 = cnt[4 * tid], c1 = cnt[4 * tid + 1];
    unsigned int c2 = cnt[4 * tid + 2], c3 = cnt[4 * tid + 3];
    unsigned int s = c0 + c1 + c2 + c3, p = s;
    #pragma unroll
    for (int off = 1; off < 64; off <<= 1) {
        unsigned int v = __shfl_up(p, off);
        if (lane >= off) p += v;
    }
    if (lane == 63) wtot[wid] = p;
    __syncthreads();
    if (tid == 0) { unsigned int r = 0;
        #pragma unroll
        for (int q = 0; q < 4; q++) { wo[q] = r; r += wtot[q]; } }
    __syncthreads();
    unsigned int ex = wo[wid] + (p - s);
    pref[4 * tid]     = ex;
    pref[4 * tid + 1] = ex + c0;
    pref[4 * tid + 2] = ex + c0 + c1;
    pref[4 * tid + 3] = ex + c0 + c1 + c2;
    runstart[bid * NBINS + 4 * tid]     = (unsigned short)ex;       // coalesced 8B
    runstart[bid * NBINS + 4 * tid + 1] = (unsigned short)(ex + c0);
    runstart[bid * NBINS + 4 * tid + 2] = (unsigned short)(ex + c0 + c1);
    runstart[bid * NBINS + 4 * tid + 3] = (unsigned short)(ex + c0 + c1 + c2);
    __syncthreads();
    #pragma unroll
    for (int j = 0; j < 4; j++) cnt[4 * tid + j] = 0u;  // reuse as rank counters
    __syncthreads();

    #pragma unroll
    for (int k = 0; k < 6; k++) {
        unsigned int v = it[k], bin = v >> 16;
        unsigned int r = atomicAdd(&cnt[bin], 1u);
        items[pref[bin] + r] = v;
    }
    __syncthreads();

    #pragma unroll
    for (int k = 0; k < 6; k++)                    // fully coalesced flush
        bigbin[bid * IPB + k * 256 + tid] = items[k * 256 + tid];

    // fused: s0 = inputs @ lin_w.T + lin_b  (2048 waves x 2 rows)
    #pragma unroll
    for (int r = 0; r < 2; r++) {
        int row = (bid * 4 + wid) * 2 + r;
        const float* rp = inputs + row * ADIM;
        float v = rp[lane] * lin_w[lane] + rp[lane + 64] * lin_w[lane + 64];
        #pragma unroll
        for (int off = 32; off > 0; off >>= 1) v += __shfl_down(v, off);
        if (lane == 0) s0[row] = v + lin_b[0];
    }
}

// ---- k_l0: balanced descriptor-scatter + uniform flat loop ------------------
// Scan the 512 run lengths, scatter global item INDICES into a flat LDS array
// at prefix positions, then process with a block-strided loop (all lanes
// active, independent loads -> MLP). PROCESS identical to R22 (telescoping
// dedup + register accumulation).
__global__ __launch_bounds__(256) void k_l0(const unsigned short* __restrict__ runstart,
                                            const unsigned int* __restrict__ bigbin,
                                            unsigned int* __restrict__ cnt2,
                                            unsigned short* __restrict__ entries2,
                                            const float* __restrict__ s_in,
                                            const float* __restrict__ att_w,
                                            const float* __restrict__ edge_emb,
                                            float* __restrict__ s_out) {
    __shared__ unsigned int mask[RPB2][512];       // 8 KB nibble-mask
    __shared__ unsigned int flat[FCAP];            // 8 KB global item indices
    __shared__ unsigned short ownerc[RPB2][OCAP];  // 4 KB owner cols
    __shared__ unsigned int rcnt[RPB2];
    __shared__ unsigned int wtot[4], wo[4], nT;
    __shared__ float accw[4][16];                  // per-wave partials
    __shared__ float accT[16];
    __shared__ float lut0[8], lut1[8], wc4[4], Sred[4], arow[RPB2][2];
    int tid = threadIdx.x, bid = blockIdx.x;
    int lane = tid & 63, wid = tid >> 6;

    if (tid < 16) {                                // layer 0 constants
        int h = tid >> 3, m = tid & 7;
        const float* w = att_w + h * (DD + 2);
        float e0 = 0.f, e1 = 0.f, e2 = 0.f;
        #pragma unroll
        for (int d = 0; d < DD; d++) {
            float wd = w[1 + d];
            e0 += edge_emb[0 * DD + d] * wd;
            e1 += edge_emb[1 * DD + d] * wd;
            e2 += edge_emb[2 * DD + d] * wd;
        }
        float l = (m & 1 ? e0 : 0.f) + (m & 2 ? e1 : 0.f) + (m & 4 ? e2 : 0.f);
        if (h) lut1[m] = l; else lut0[m] = l;
        if (m == 0) { wc4[h] = w[0]; wc4[2 + h] = w[DD + 1]; }
    }
    if (tid < RPB2) rcnt[tid] = 0u;
    #pragma unroll
    for (int i = 0; i < 8; i++)                    // zero 8 KB mask
        ((unsigned int*)mask)[i * 256 + tid] = 0u;

    float ps = 0.f;                                // S = sum(s_in)
    #pragma unroll
    for (int i = 0; i < 16; i++) ps += s_in[i * 256 + tid];
    #pragma unroll
    for (int off = 32; off > 0; off >>= 1) ps += __shfl_down(ps, off);
    if (lane == 0) Sred[wid] = ps;

    // ---- run boundaries for this bin (2 segments per thread) ----
    unsigned int st0 = runstart[(size_t)tid * NBINS + bid];
    unsigned int st1 = runstart[(size_t)(256 + tid) * NBINS + bid];
    unsigned int en0, en1;
    if (bid == NBINS - 1) { en0 = IPB; en1 = IPB; }
    else {
        en0 = runstart[(size_t)tid * NBINS + bid + 1];
        en1 = runstart[(size_t)(256 + tid) * NBINS + bid + 1];
    }
    unsigned int len0 = en0 - st0, len1 = en1 - st1;

    // block scan of (len0+len1) -> scatter positions
    unsigned int s2 = len0 + len1, p = s2;
    #pragma unroll
    for (int off = 1; off < 64; off <<= 1) {
        unsigned int v = __shfl_up(p, off);
        if (lane >= off) p += v;
    }
    if (lane == 63) wtot[wid] = p;
    __syncthreads();                               // wtot + Sred + mask ready
    if (tid == 0) {
        unsigned int r = 0;
        #pragma unroll
        for (int q = 0; q < 4; q++) { wo[q] = r; r += wtot[q]; }
        nT = r;
    }
    float S = Sred[0] + Sred[1] + Sred[2] + Sred[3];
    if (tid < RPB2) {                              // per-row a-terms
        float si = s_in[bid * RPB2 + tid];
        arow[tid][0] = wc4[0] * si;
        arow[tid][1] = wc4[1] * si;
    }
    __syncthreads();                               // wo/nT/arow ready

    unsigned int ex = wo[wid] + (p - s2);
    unsigned int base0 = (size_t)0 + (unsigned int)tid * IPB;          // blk = tid
    unsigned int base1 = (unsigned int)(256 + tid) * IPB;              // blk = tid+256
    for (unsigned int j = 0; j < len0; j++) flat[ex + j] = base0 + st0 + j;
    ex += len0;
    for (unsigned int j = 0; j < len1; j++) flat[ex + j] = base1 + st1 + j;
    __syncthreads();
    unsigned int n = min(nT, (unsigned int)FCAP);

    // 16 register accumulators: n<h><row>, d<h><row>
    float n00 = 0.f, d00 = 0.f, n10 = 0.f, d10 = 0.f;
    float n01 = 0.f, d01 = 0.f, n11 = 0.f, d11 = 0.f;
    float n02 = 0.f, d02 = 0.f, n12 = 0.f, d12 = 0.f;
    float n03 = 0.f, d03 = 0.f, n13 = 0.f, d13 = 0.f;
    float b0 = wc4[2], b1 = wc4[3];

    for (unsigned int i = tid; i < n; i += 256) {  // uniform flat loop
        unsigned int v = bigbin[flat[i]];
        unsigned int lr = (v >> 14) & 3u;
        unsigned int col = (v >> 2) & 0xFFFu;
        unsigned int t = v & 3u;
        unsigned int sh = (col & 7u) << 2;
        unsigned int bit = 1u << (sh + t);
        unsigned int old = atomicOr(&mask[lr][col >> 3], bit);
        if (old & bit) continue;                   // duplicate (pair,type)
        unsigned int oldnib = (old >> sh) & 0xFu;
        unsigned int newnib = oldnib | (1u << t);
        float sj = s_in[col];
        float a0 = arow[lr][0], a1 = arow[lr][1];
        float cn = (float)__popc(newnib);
        float l0n = cn * (a0 + b0 * sj) + lut0[newnib];
        l0n = (l0n > 0.f) ? l0n : NEG * l0n;
        float x0 = __expf(l0n) - 1.0f;
        float l1n = cn * (a1 + b1 * sj) + lut1[newnib];
        l1n = (l1n > 0.f) ? l1n : NEG * l1n;
        float x1 = __expf(l1n) - 1.0f;
        if (oldnib) {                              // rare: subtract f(old)
            float co = (float)__popc(oldnib);
            float l0o = co * (a0 + b0 * sj) + lut0[oldnib];
            l0o = (l0o > 0.f) ? l0o : NEG * l0o;
            x0 -= __expf(l0o) - 1.0f;
            float l1o = co * (a1 + b1 * sj) + lut1[oldnib];
            l1o = (l1o > 0.f) ? l1o : NEG * l1o;
            x1 -= __expf(l1o) - 1.0f;
        } else {                                   // first bit: owner append
            unsigned int r = atomicAdd(&rcnt[lr], 1u);
            if (r < OCAP) ownerc[lr][r] = (unsigned short)col;
        }
        float v0f = x0 * sj, v1f = x1 * sj;
        if (lr == 0)      { n00 += v0f; d00 += x0; n10 += v1f; d10 += x1; }
        else if (lr == 1) { n01 += v0f; d01 += x0; n11 += v1f; d11 += x1; }
        else if (lr == 2) { n02 += v0f; d02 += x0; n12 += v1f; d12 += x1; }
        else              { n03 += v0f; d03 += x0; n13 += v1f; d13 += x1; }
    }

    // wave-reduce the 16 accumulators (uniform control flow)
    n00 = wred(n00); d00 = wred(d00); n10 = wred(n10); d10 = wred(d10);
    n01 = wred(n01); d01 = wred(d01); n11 = wred(n11); d11 = wred(d11);
    n02 = wred(n02); d02 = wred(d02); n12 = wred(n12); d12 = wred(d12);
    n03 = wred(n03); d03 = wred(d03); n13 = wred(n13); d13 = wred(d13);
    if (lane == 0) {
        float* aw = accw[wid];
        aw[0]  = n00; aw[1]  = d00; aw[2]  = n10; aw[3]  = d10;
        aw[4]  = n01; aw[5]  = d01; aw[6]  = n11; aw[7]  = d11;
        aw[8]  = n02; aw[9]  = d02; aw[10] = n12; aw[11] = d12;
        aw[12] = n03; aw[13] = d03; aw[14] = n13; aw[15] = d13;
    }
    __syncthreads();
    if (tid < 16)                                  // deterministic cross-wave sum
        accT[tid] = accw[0][tid] + accw[1][tid] + accw[2][tid] + accw[3][tid];
    __syncthreads();

    // fixup: read final nibbles, emit CSR coalesced
    #pragma unroll
    for (int lr = 0; lr < RPB2; lr++) {
        int row = bid * RPB2 + lr;
        unsigned int nn = min(rcnt[lr], (unsigned int)OCAP);
        for (unsigned int i = tid; i < nn; i += 256) {
            unsigned int col = ownerc[lr][i];
            unsigned int nib = (mask[lr][col >> 3] >> ((col & 7u) << 2)) & 0xFu;
            entries2[(size_t)row * CAP + i] = (unsigned short)(col | (nib << 12));
        }
    }
    if (tid < RPB2) {
        int row = bid * RPB2 + tid;
        float o0 = (S + accT[tid * 4 + 0]) / ((float)NN + accT[tid * 4 + 1]);
        float o1 = (S + accT[tid * 4 + 2]) / ((float)NN + accT[tid * 4 + 3]);
        s_out[row] = 0.5f * (o0 + o1);
        cnt2[row] = min(rcnt[tid], (unsigned int)CAP);
    }
}

// ---- k_l1: layer 1 over compact CSR (row per wave) --------------------------
__global__ __launch_bounds__(256) void k_l1(const unsigned int* __restrict__ cnt2,
                                            const unsigned short* __restrict__ entries2,
                                            const float* __restrict__ s_in,
                                            const float* __restrict__ att_w,
                                            const float* __restrict__ edge_emb,
                                            float* __restrict__ s_out) {
    __shared__ float lut0[8], lut1[8], wc4[4], Sred[4];
    int tid = threadIdx.x;

    if (tid < 16) {                                // layer 1 constants
        int h = tid >> 3, m = tid & 7;
        const float* w = att_w + (2 + h) * (DD + 2);
        float e0 = 0.f, e1 = 0.f, e2 = 0.f;
        #pragma unroll
        for (int d = 0; d < DD; d++) {
            float wd = w[1 + d];
            e0 += edge_emb[0 * DD + d] * wd;
            e1 += edge_emb[1 * DD + d] * wd;
            e2 += edge_emb[2 * DD + d] * wd;
        }
        float l = (m & 1 ? e0 : 0.f) + (m & 2 ? e1 : 0.f) + (m & 4 ? e2 : 0.f);
        if (h) lut1[m] = l; else lut0[m] = l;
        if (m == 0) { wc4[h] = w[0]; wc4[2 + h] = w[DD + 1]; }
    }

    float ps = 0.f;
    for (int j = tid; j < NN; j += 256) ps += s_in[j];
    #pragma unroll
    for (int off = 32; off > 0; off >>= 1) ps += __shfl_down(ps, off);
    int wid = tid >> 6, lane = tid & 63;
    if (lane == 0) Sred[wid] = ps;
    __syncthreads();
    float S = Sred[0] + Sred[1] + Sred[2] + Sred[3];

    int row = blockIdx.x * 4 + wid;
    float si = s_in[row];
    float a0 = wc4[0] * si, a1 = wc4[1] * si;
    float b0 = wc4[2],      b1 = wc4[3];
    unsigned int n = cnt2[row];
    const unsigned short* ent = entries2 + (size_t)row * CAP;

    float num0 = 0.f, den0 = 0.f, num1 = 0.f, den1 = 0.f;
    for (unsigned int i = lane; i < n; i += 64) {
        unsigned int v = ent[i];
        unsigned int j = v & 0xFFFu, nib = v >> 12;
        float c  = (float)__popc(nib);
        float sj = s_in[j];
        float l0 = c * (a0 + b0 * sj) + lut0[nib];
        l0 = (l0 > 0.f) ? l0 : NEG * l0;
        float x0 = __expf(l0) - 1.0f;
        num0 += x0 * sj; den0 += x0;
        float l1 = c * (a1 + b1 * sj) + lut1[nib];
        l1 = (l1 > 0.f) ? l1 : NEG * l1;
        float x1 = __expf(l1) - 1.0f;
        num1 += x1 * sj; den1 += x1;
    }

    #pragma unroll
    for (int off = 32; off > 0; off >>= 1) {
        num0 += __shfl_down(num0, off); den0 += __shfl_down(den0, off);
        num1 += __shfl_down(num1, off); den1 += __shfl_down(den1, off);
    }
    if (lane == 0) {
        float o0 = (S + num0) / ((float)NN + den0);
        float o1 = (S + num1) / ((float)NN + den1);
        s_out[row] = 0.5f * (o0 + o1);
    }
}

// ---- host-side launcher ------------------------------------------------------
extern "C" void kernel_launch(void* const* d_in, const int* in_sizes, int n_in,
                              void* d_out, int out_size, void* d_ws, size_t ws_size,
                              hipStream_t stream) {
    const float* inputs   = (const float*)d_in[0];
    const float* lin_w    = (const float*)d_in[1];
    const float* lin_b    = (const float*)d_in[2];
    const float* edge_emb = (const float*)d_in[3];
    const float* att_w    = (const float*)d_in[4];
    const int*   el       = (const int*)d_in[5];
    float* out = (float*)d_out;

    char* ws = (char*)d_ws;
    unsigned short* runstart = (unsigned short*)ws;                       // 1 MB
    unsigned int*   bigbin   = (unsigned int*)(ws + 1048576);             // 3 MB
    unsigned short* entries2 = (unsigned short*)(ws + 4194304);           // 4 MB
    unsigned int*   cnt2     = (unsigned int*)(ws + 8388608);             // 16 KB
    float*          s0       = (float*)(ws + 8404992);                    // 16 KB
    float*          s1       = (float*)(ws + 8421376);                    // 16 KB

    k_bin<<<NBB, 256, 0, stream>>>(el, runstart, bigbin, inputs, lin_w, lin_b, s0);
    k_l0 <<<NBINS, 256, 0, stream>>>(runstart, bigbin, cnt2, entries2,
                                     s0, att_w, edge_emb, s1);
    k_l1 <<<1024, 256, 0, stream>>>(cnt2, entries2, s1, att_w, edge_emb, out);
}